// Round 1
// baseline (6704.502 us; speedup 1.0000x reference)
//
#include <hip/hip_runtime.h>
#include <math.h>

#define HID 64

// ---------------------------------------------------------------------------
// Node encoder: out = relu(feat @ W1 + b1) @ W2 + b2,  feat [N,2]
// ---------------------------------------------------------------------------
__global__ __launch_bounds__(256) void enc_kernel(
    const float* __restrict__ feat, const float* __restrict__ W1,
    const float* __restrict__ b1, const float* __restrict__ W2,
    const float* __restrict__ b2, float* __restrict__ out, int N)
{
    __shared__ float sW2[64 * 64];
    __shared__ float sh1[64 * 64];   // [n][j]; reads are broadcast, no pad needed
    const int n0 = blockIdx.x * 64;
    const int t = threadIdx.x;
    for (int idx = t; idx < 4096; idx += 256) sW2[idx] = W2[idx];
    for (int idx = t; idx < 4096; idx += 256) {
        int n = idx >> 6, j = idx & 63;
        int gn = n0 + n;
        float v = 0.f;
        if (gn < N) {
            float f0 = feat[gn * 2 + 0], f1 = feat[gn * 2 + 1];
            v = fmaxf(fmaf(f0, W1[j], fmaf(f1, W1[64 + j], b1[j])), 0.f);
        }
        sh1[idx] = v;
    }
    __syncthreads();
    for (int idx = t; idx < 4096; idx += 256) {
        int n = idx >> 6, k = idx & 63;
        int gn = n0 + n;
        if (gn >= N) continue;
        float acc = b2[k];
        const float* hrow = &sh1[n * 64];
        #pragma unroll 8
        for (int j = 0; j < 64; ++j) acc = fmaf(hrow[j], sW2[j * 64 + k], acc);
        out[gn * 64 + k] = acc;
    }
}

// ---------------------------------------------------------------------------
// Build interval tables for the scalar-input edge MLP.
// h1_j(e) = relu(e*a_j + b_j) is active on a half-line; sorting the 64
// thresholds t_j=-b_j/a_j gives 65 intervals with constant active mask.
// h_k(e) = relu(e*P[iv][k] + Q[iv][k]),  iv = #{ t_j < e }   (exact algebra)
// Also zeroes the BN stats buffer for the following stats pass.
// ---------------------------------------------------------------------------
__global__ __launch_bounds__(256) void build_tables_kernel(
    const float* __restrict__ eW1, const float* __restrict__ eb1,
    const float* __restrict__ eW2, const float* __restrict__ eb2,
    float* __restrict__ P, float* __restrict__ Q,
    float* __restrict__ sortedT, float* __restrict__ stats)
{
    __shared__ float sa[64], sb[64], sT[64];
    __shared__ int srank[64];
    const int t = threadIdx.x;
    if (t < 128) stats[t] = 0.f;
    if (t < 64) {
        float a = eW1[t], b = eb1[t];
        sa[t] = a; sb[t] = b;
        sT[t] = (a != 0.f) ? (-b / a) : INFINITY;   // a==0: no threshold
    }
    __syncthreads();
    if (t < 64) {
        float Tj = sT[t];
        int r = 0;
        for (int i = 0; i < 64; ++i) {
            float Ti = sT[i];
            r += (Ti < Tj || (Ti == Tj && i < t)) ? 1 : 0;   // stable rank
        }
        srank[t] = r;
        sortedT[r] = Tj;
    }
    __syncthreads();
    for (int idx = t; idx < 65 * 64; idx += 256) {
        int iv = idx >> 6, k = idx & 63;
        float accP = 0.f, accQ = 0.f;
        for (int j = 0; j < 64; ++j) {
            float a = sa[j];
            // a>0: active iff t_j < e  <=> rank < iv ; a<0: active iff e < t_j
            bool act = (a > 0.f) ? (srank[j] < iv)
                                 : ((a < 0.f) ? (srank[j] >= iv) : (sb[j] > 0.f));
            if (act) {
                float w = eW2[j * 64 + k];
                accP = fmaf(a, w, accP);
                accQ = fmaf(sb[j], w, accQ);
            }
        }
        P[idx] = accP;
        Q[idx] = accQ + eb2[k];
    }
}

__device__ __forceinline__ int interval_of(const float* sT, float ev)
{
    int iv = 0;
    #pragma unroll
    for (int s = 32; s >= 1; s >>= 1)
        if (iv + s <= 64 && sT[iv + s - 1] < ev) iv += s;
    return iv;   // = #{ T < ev }
}

// ---------------------------------------------------------------------------
// BN stats pass: per-feature sum and sum-of-squares of h over all edges.
// Wave = one edge per iteration, lane = feature.
// ---------------------------------------------------------------------------
__global__ __launch_bounds__(256) void edge_stats_kernel(
    const float* __restrict__ ef, const float* __restrict__ P,
    const float* __restrict__ Q, const float* __restrict__ sortedT,
    float* __restrict__ stats, int E)
{
    __shared__ float sP[65 * 64], sQ[65 * 64], sT[64];
    __shared__ float red[2][4][64];
    const int t = threadIdx.x;
    for (int idx = t; idx < 65 * 64; idx += 256) { sP[idx] = P[idx]; sQ[idx] = Q[idx]; }
    if (t < 64) sT[t] = sortedT[t];
    __syncthreads();
    const int lane = t & 63, wave = t >> 6;
    const int gw = blockIdx.x * 4 + wave;
    const int nW = gridDim.x * 4;
    float sum = 0.f, sq = 0.f;
    for (int eid = gw; eid < E; eid += nW) {
        float ev = ef[eid];
        int iv = interval_of(sT, ev);
        float h = fmaxf(fmaf(ev, sP[iv * 64 + lane], sQ[iv * 64 + lane]), 0.f);
        sum += h; sq = fmaf(h, h, sq);
    }
    red[0][wave][lane] = sum;
    red[1][wave][lane] = sq;
    __syncthreads();
    if (t < 64) {
        float s0 = red[0][0][t] + red[0][1][t] + red[0][2][t] + red[0][3][t];
        atomicAdd(&stats[t], s0);
    } else if (t < 128) {
        int k = t - 64;
        float s1 = red[1][0][k] + red[1][1][k] + red[1][2][k] + red[1][3][k];
        atomicAdd(&stats[64 + k], s1);
    }
}

// stats -> BN scale/shift:  emb = h*s + tt
__global__ void bn_finalize_kernel(
    const float* __restrict__ stats, const float* __restrict__ g,
    const float* __restrict__ bt, float* __restrict__ st, float En)
{
    int k = threadIdx.x;
    if (k < 64) {
        float mu = stats[k] / En;
        float var = fmaxf(stats[64 + k] / En - mu * mu, 0.f);
        float s = g[k] / sqrtf(var + 1e-5f);
        st[k] = s;
        st[64 + k] = fmaf(-mu, s, bt[k]);
    }
}

// ---------------------------------------------------------------------------
// Main edge pass: msg = relu(src[ei0] + h*s + tt); atomic scatter into agg.
// ---------------------------------------------------------------------------
__global__ __launch_bounds__(256) void edge_pass_kernel(
    const float* __restrict__ ef, const int* __restrict__ ei,
    const float* __restrict__ src, const float* __restrict__ P,
    const float* __restrict__ Q, const float* __restrict__ sortedT,
    const float* __restrict__ st, float* __restrict__ agg, int E)
{
    __shared__ float sP[65 * 64], sQ[65 * 64], sT[64], ss[64], stt[64];
    const int t = threadIdx.x;
    for (int idx = t; idx < 65 * 64; idx += 256) { sP[idx] = P[idx]; sQ[idx] = Q[idx]; }
    if (t < 64) { sT[t] = sortedT[t]; ss[t] = st[t]; stt[t] = st[64 + t]; }
    __syncthreads();
    const int lane = t & 63, wave = t >> 6;
    const int gw = blockIdx.x * 4 + wave;
    const int nW = gridDim.x * 4;
    for (int eid = gw; eid < E; eid += nW) {
        float ev = ef[eid];
        int i0 = ei[eid];
        int i1 = ei[E + eid];
        int iv = interval_of(sT, ev);
        float h = fmaxf(fmaf(ev, sP[iv * 64 + lane], sQ[iv * 64 + lane]), 0.f);
        float emb = fmaf(h, ss[lane], stt[lane]);
        float msg = fmaxf(src[i0 * 64 + lane] + emb, 0.f);
        atomicAdd(&agg[i1 * 64 + lane], msg);
    }
}

// degree count (as float; exact for counts < 2^24) and inverse transform
__global__ void count_kernel(const int* __restrict__ tgt_idx,
                             float* __restrict__ cnt, int E)
{
    int i = blockIdx.x * blockDim.x + threadIdx.x;
    if (i < E) atomicAdd(&cnt[tgt_idx[i]], 1.0f);
}
__global__ void inv_kernel(float* __restrict__ cnt, int N)
{
    int i = blockIdx.x * blockDim.x + threadIdx.x;
    if (i < N) cnt[i] = 1.f / fmaxf(cnt[i], 1.f);
}

// ---------------------------------------------------------------------------
// combine: tgt_new = relu(L2normalize((agg*inv) @ lW + lb + tgt @ rW))
// In-place on tgt (each block owns its 64 rows).
// ---------------------------------------------------------------------------
__global__ __launch_bounds__(256) void combine_kernel(
    const float* __restrict__ agg, const float* __restrict__ inv,
    float* __restrict__ tgt, const float* __restrict__ lW,
    const float* __restrict__ lb, const float* __restrict__ rW, int N)
{
    __shared__ float sLW[64 * 64], sRW[64 * 64];
    __shared__ float sM[64][65], sTg[64][65], sO[64][65];
    __shared__ float srn[64];
    const int n0 = blockIdx.x * 64;
    const int t = threadIdx.x;
    for (int idx = t; idx < 4096; idx += 256) { sLW[idx] = lW[idx]; sRW[idx] = rW[idx]; }
    for (int idx = t; idx < 4096; idx += 256) {
        int n = idx >> 6, j = idx & 63;
        int gn = n0 + n;
        float m = 0.f, tv = 0.f;
        if (gn < N) {
            m = agg[gn * 64 + j] * inv[gn];
            tv = tgt[gn * 64 + j];
        }
        sM[n][j] = m; sTg[n][j] = tv;
    }
    __syncthreads();
    const int n = t & 63;
    for (int m4 = 0; m4 < 4; ++m4) {
        int k4 = (t >> 6) + m4 * 4;          // 0..15
        float o0 = 0, o1 = 0, o2 = 0, o3 = 0;
        const float* mr = sM[n];
        const float* tr = sTg[n];
        #pragma unroll 8
        for (int j = 0; j < 64; ++j) {
            float mv = mr[j];
            float4 w4 = *reinterpret_cast<const float4*>(&sLW[j * 64 + k4 * 4]);
            o0 = fmaf(mv, w4.x, o0); o1 = fmaf(mv, w4.y, o1);
            o2 = fmaf(mv, w4.z, o2); o3 = fmaf(mv, w4.w, o3);
        }
        #pragma unroll 8
        for (int j = 0; j < 64; ++j) {
            float tv = tr[j];
            float4 w4 = *reinterpret_cast<const float4*>(&sRW[j * 64 + k4 * 4]);
            o0 = fmaf(tv, w4.x, o0); o1 = fmaf(tv, w4.y, o1);
            o2 = fmaf(tv, w4.z, o2); o3 = fmaf(tv, w4.w, o3);
        }
        int kb = k4 * 4;
        sO[n][kb + 0] = o0 + lb[kb + 0];
        sO[n][kb + 1] = o1 + lb[kb + 1];
        sO[n][kb + 2] = o2 + lb[kb + 2];
        sO[n][kb + 3] = o3 + lb[kb + 3];
    }
    __syncthreads();
    if (t < 64) {
        float s = 0.f;
        for (int j = 0; j < 64; ++j) { float v = sO[t][j]; s = fmaf(v, v, s); }
        srn[t] = 1.f / fmaxf(sqrtf(s), 1e-12f);
    }
    __syncthreads();
    for (int idx = t; idx < 4096; idx += 256) {
        int nn = idx >> 6, k = idx & 63;
        int gn = n0 + nn;
        if (gn < N) tgt[gn * 64 + k] = fmaxf(sO[nn][k] * srn[nn], 0.f);
    }
}

// ---------------------------------------------------------------------------
// acc (+)= X @ W   (64x64 W block of lin1)
// ---------------------------------------------------------------------------
template <bool INIT>
__global__ __launch_bounds__(256) void acc_gemm_kernel(
    const float* __restrict__ X, const float* __restrict__ W,
    float* __restrict__ acc, int N)
{
    __shared__ float sW[64 * 64];
    __shared__ float sX[64][65];
    const int n0 = blockIdx.x * 64;
    const int t = threadIdx.x;
    for (int idx = t; idx < 4096; idx += 256) sW[idx] = W[idx];
    for (int idx = t; idx < 4096; idx += 256) {
        int n = idx >> 6, j = idx & 63;
        int gn = n0 + n;
        sX[n][j] = (gn < N) ? X[gn * 64 + j] : 0.f;
    }
    __syncthreads();
    const int n = t & 63;
    const int gn = n0 + n;
    for (int m4 = 0; m4 < 4; ++m4) {
        int k4 = (t >> 6) + m4 * 4;
        float o0 = 0, o1 = 0, o2 = 0, o3 = 0;
        const float* xr = sX[n];
        #pragma unroll 8
        for (int j = 0; j < 64; ++j) {
            float xv = xr[j];
            float4 w4 = *reinterpret_cast<const float4*>(&sW[j * 64 + k4 * 4]);
            o0 = fmaf(xv, w4.x, o0); o1 = fmaf(xv, w4.y, o1);
            o2 = fmaf(xv, w4.z, o2); o3 = fmaf(xv, w4.w, o3);
        }
        if (gn < N) {
            float4* ap = reinterpret_cast<float4*>(&acc[gn * 64 + k4 * 4]);
            if (INIT) {
                *ap = make_float4(o0, o1, o2, o3);
            } else {
                float4 old = *ap;
                *ap = make_float4(old.x + o0, old.y + o1, old.z + o2, old.w + o3);
            }
        }
    }
}

// ---------------------------------------------------------------------------
// final head: relu(acc+b1) -> relu(@W2+b2) -> relu(@W3+b3) -> @W4+b4 -> logsoftmax
// ---------------------------------------------------------------------------
__global__ __launch_bounds__(256) void final_kernel(
    const float* __restrict__ acc, const float* __restrict__ b1,
    const float* __restrict__ W2, const float* __restrict__ b2,
    const float* __restrict__ W3, const float* __restrict__ b3,
    const float* __restrict__ W4, const float* __restrict__ b4,
    float* __restrict__ out, int N)
{
    __shared__ float sW[64 * 64];
    __shared__ float sA[64][65], sB[64][65];
    __shared__ float sy[64][2];
    const int n0 = blockIdx.x * 64;
    const int t = threadIdx.x;
    for (int idx = t; idx < 4096; idx += 256) sW[idx] = W2[idx];
    for (int idx = t; idx < 4096; idx += 256) {
        int n = idx >> 6, j = idx & 63;
        int gn = n0 + n;
        sA[n][j] = (gn < N) ? fmaxf(acc[gn * 64 + j] + b1[j], 0.f) : 0.f;
    }
    __syncthreads();
    const int n = t & 63;
    // z2 = relu(z1@W2+b2) -> sB
    for (int m4 = 0; m4 < 4; ++m4) {
        int k4 = (t >> 6) + m4 * 4;
        float o0 = 0, o1 = 0, o2 = 0, o3 = 0;
        const float* xr = sA[n];
        #pragma unroll 8
        for (int j = 0; j < 64; ++j) {
            float xv = xr[j];
            float4 w4 = *reinterpret_cast<const float4*>(&sW[j * 64 + k4 * 4]);
            o0 = fmaf(xv, w4.x, o0); o1 = fmaf(xv, w4.y, o1);
            o2 = fmaf(xv, w4.z, o2); o3 = fmaf(xv, w4.w, o3);
        }
        int kb = k4 * 4;
        sB[n][kb + 0] = fmaxf(o0 + b2[kb + 0], 0.f);
        sB[n][kb + 1] = fmaxf(o1 + b2[kb + 1], 0.f);
        sB[n][kb + 2] = fmaxf(o2 + b2[kb + 2], 0.f);
        sB[n][kb + 3] = fmaxf(o3 + b2[kb + 3], 0.f);
    }
    __syncthreads();
    for (int idx = t; idx < 4096; idx += 256) sW[idx] = W3[idx];
    __syncthreads();
    // z3 = relu(z2@W3+b3) -> sA
    for (int m4 = 0; m4 < 4; ++m4) {
        int k4 = (t >> 6) + m4 * 4;
        float o0 = 0, o1 = 0, o2 = 0, o3 = 0;
        const float* xr = sB[n];
        #pragma unroll 8
        for (int j = 0; j < 64; ++j) {
            float xv = xr[j];
            float4 w4 = *reinterpret_cast<const float4*>(&sW[j * 64 + k4 * 4]);
            o0 = fmaf(xv, w4.x, o0); o1 = fmaf(xv, w4.y, o1);
            o2 = fmaf(xv, w4.z, o2); o3 = fmaf(xv, w4.w, o3);
        }
        int kb = k4 * 4;
        sA[n][kb + 0] = fmaxf(o0 + b3[kb + 0], 0.f);
        sA[n][kb + 1] = fmaxf(o1 + b3[kb + 1], 0.f);
        sA[n][kb + 2] = fmaxf(o2 + b3[kb + 2], 0.f);
        sA[n][kb + 3] = fmaxf(o3 + b3[kb + 3], 0.f);
    }
    __syncthreads();
    if (t < 128) {
        int nn = t >> 1, c = t & 1;
        float a = b4[c];
        for (int j = 0; j < 64; ++j) a = fmaf(sA[nn][j], W4[j * 2 + c], a);
        sy[nn][c] = a;
    }
    __syncthreads();
    if (t < 64) {
        int gn = n0 + t;
        if (gn < N) {
            float y0 = sy[t][0], y1 = sy[t][1];
            float m = fmaxf(y0, y1);
            float lse = m + logf(expf(y0 - m) + expf(y1 - m));
            out[gn * 2 + 0] = y0 - lse;
            out[gn * 2 + 1] = y1 - lse;
        }
    }
}

// ---------------------------------------------------------------------------
extern "C" void kernel_launch(void* const* d_in, const int* in_sizes, int n_in,
                              void* d_out, int out_size, void* d_ws, size_t ws_size,
                              hipStream_t stream)
{
    const float* varf    = (const float*)d_in[0];
    const float* conf    = (const float*)d_in[1];
    const float* ev_feat = (const float*)d_in[2];
    const float* ec_feat = (const float*)d_in[3];
    const int*   ei_var  = (const int*)d_in[4];
    const int*   ei_con  = (const int*)d_in[5];
    const float* enc_v_W1 = (const float*)d_in[6];
    const float* enc_v_b1 = (const float*)d_in[7];
    const float* enc_v_W2 = (const float*)d_in[8];
    const float* enc_v_b2 = (const float*)d_in[9];
    const float* enc_c_W1 = (const float*)d_in[10];
    const float* enc_c_b1 = (const float*)d_in[11];
    const float* enc_c_W2 = (const float*)d_in[12];
    const float* enc_c_b2 = (const float*)d_in[13];
    const float* lv_eW1 = (const float*)d_in[14];
    const float* lv_eb1 = (const float*)d_in[15];
    const float* lv_eW2 = (const float*)d_in[16];
    const float* lv_eb2 = (const float*)d_in[17];
    const float* lv_g   = (const float*)d_in[18];
    const float* lv_bt  = (const float*)d_in[19];
    const float* lv_lW  = (const float*)d_in[20];
    const float* lv_lb  = (const float*)d_in[21];
    const float* lv_rW  = (const float*)d_in[22];
    const float* lc_eW1 = (const float*)d_in[23];
    const float* lc_eb1 = (const float*)d_in[24];
    const float* lc_eW2 = (const float*)d_in[25];
    const float* lc_eb2 = (const float*)d_in[26];
    const float* lc_g   = (const float*)d_in[27];
    const float* lc_bt  = (const float*)d_in[28];
    const float* lc_lW  = (const float*)d_in[29];
    const float* lc_lb  = (const float*)d_in[30];
    const float* lc_rW  = (const float*)d_in[31];
    const float* lin1_W = (const float*)d_in[32];
    const float* lin1_b = (const float*)d_in[33];
    const float* lin2_W = (const float*)d_in[34];
    const float* lin2_b = (const float*)d_in[35];
    const float* lin3_W = (const float*)d_in[36];
    const float* lin3_b = (const float*)d_in[37];
    const float* lin4_W = (const float*)d_in[38];
    const float* lin4_b = (const float*)d_in[39];

    const int Nv = in_sizes[0] / 2, Nc = in_sizes[1] / 2;
    const int Ev = in_sizes[2], Ec = in_sizes[3];
    const int maxN = (Nv > Nc) ? Nv : Nc;

    float* ws = (float*)d_ws;
    float* xv  = ws;  ws += (size_t)Nv * 64;
    float* xc  = ws;  ws += (size_t)Nc * 64;
    float* agg = ws;  ws += (size_t)maxN * 64;
    float* acc = ws;  ws += (size_t)Nv * 64;
    float* inv_c = ws; ws += Nc;
    float* inv_v = ws; ws += Nv;
    float* stats = ws; ws += 128;
    float* stv   = ws; ws += 128;
    float* P = ws;       ws += 65 * 64;
    float* Q = ws;       ws += 65 * 64;
    float* sortedT = ws; ws += 64;

    const dim3 blk(256);
    const int gbV = (Nv + 63) / 64, gbC = (Nc + 63) / 64;

    enc_kernel<<<gbV, blk, 0, stream>>>(varf, enc_v_W1, enc_v_b1, enc_v_W2, enc_v_b2, xv, Nv);
    enc_kernel<<<gbC, blk, 0, stream>>>(conf, enc_c_W1, enc_c_b1, enc_c_W2, enc_c_b2, xc, Nc);
    hipMemsetAsync(inv_c, 0, (size_t)Nc * sizeof(float), stream);
    hipMemsetAsync(inv_v, 0, (size_t)Nv * sizeof(float), stream);
    count_kernel<<<(Ev + 255) / 256, blk, 0, stream>>>(ei_var + Ev, inv_c, Ev);
    count_kernel<<<(Ec + 255) / 256, blk, 0, stream>>>(ei_con + Ec, inv_v, Ec);
    inv_kernel<<<(Nc + 255) / 256, blk, 0, stream>>>(inv_c, Nc);
    inv_kernel<<<(Nv + 255) / 256, blk, 0, stream>>>(inv_v, Nv);
    acc_gemm_kernel<true><<<gbV, blk, 0, stream>>>(xv, lin1_W, acc, Nv);

    for (int i = 0; i < 4; ++i) {
        // var -> con
        build_tables_kernel<<<1, blk, 0, stream>>>(lv_eW1 + i * 64, lv_eb1 + i * 64,
                                                   lv_eW2 + i * 4096, lv_eb2 + i * 64,
                                                   P, Q, sortedT, stats);
        edge_stats_kernel<<<2048, blk, 0, stream>>>(ev_feat, P, Q, sortedT, stats, Ev);
        bn_finalize_kernel<<<1, 64, 0, stream>>>(stats, lv_g + i * 64, lv_bt + i * 64, stv, (float)Ev);
        hipMemsetAsync(agg, 0, (size_t)Nc * 64 * sizeof(float), stream);
        edge_pass_kernel<<<4096, blk, 0, stream>>>(ev_feat, ei_var, xv, P, Q, sortedT, stv, agg, Ev);
        combine_kernel<<<gbC, blk, 0, stream>>>(agg, inv_c, xc, lv_lW + i * 4096,
                                                lv_lb + i * 64, lv_rW + i * 4096, Nc);
        // con -> var
        build_tables_kernel<<<1, blk, 0, stream>>>(lc_eW1 + i * 64, lc_eb1 + i * 64,
                                                   lc_eW2 + i * 4096, lc_eb2 + i * 64,
                                                   P, Q, sortedT, stats);
        edge_stats_kernel<<<2048, blk, 0, stream>>>(ec_feat, P, Q, sortedT, stats, Ec);
        bn_finalize_kernel<<<1, 64, 0, stream>>>(stats, lc_g + i * 64, lc_bt + i * 64, stv, (float)Ec);
        hipMemsetAsync(agg, 0, (size_t)Nv * 64 * sizeof(float), stream);
        edge_pass_kernel<<<4096, blk, 0, stream>>>(ec_feat, ei_con, xc, P, Q, sortedT, stv, agg, Ec);
        combine_kernel<<<gbV, blk, 0, stream>>>(agg, inv_v, xv, lc_lW + i * 4096,
                                                lc_lb + i * 64, lc_rW + i * 4096, Nv);
        acc_gemm_kernel<false><<<gbV, blk, 0, stream>>>(xv, lin1_W + (i + 1) * 4096, acc, Nv);
    }

    final_kernel<<<gbV, blk, 0, stream>>>(acc, lin1_b, lin2_W, lin2_b,
                                          lin3_W, lin3_b, lin4_W, lin4_b,
                                          (float*)d_out, Nv);
}

// Round 4
// 3901.118 us; speedup vs baseline: 1.7186x; 1.7186x over previous
//
#include <hip/hip_runtime.h>
#include <math.h>

__device__ __forceinline__ float readlane_f(float v, int l) {
    return __int_as_float(__builtin_amdgcn_readlane(__float_as_int(v), l));
}
__device__ __forceinline__ unsigned readlane_u(unsigned v, int l) {
    return (unsigned)__builtin_amdgcn_readlane((int)v, l);
}

// ---------------------------------------------------------------------------
// Node encoder: out = relu(feat @ W1 + b1) @ W2 + b2,  feat [N,2]
// ---------------------------------------------------------------------------
__global__ __launch_bounds__(256) void enc_kernel(
    const float* __restrict__ feat, const float* __restrict__ W1,
    const float* __restrict__ b1, const float* __restrict__ W2,
    const float* __restrict__ b2, float* __restrict__ out, int N)
{
    __shared__ float sW2[64 * 64];
    __shared__ float sh1[64 * 64];
    const int n0 = blockIdx.x * 64;
    const int t = threadIdx.x;
    for (int idx = t; idx < 4096; idx += 256) sW2[idx] = W2[idx];
    for (int idx = t; idx < 4096; idx += 256) {
        int n = idx >> 6, j = idx & 63;
        int gn = n0 + n;
        float v = 0.f;
        if (gn < N) {
            float f0 = feat[gn * 2 + 0], f1 = feat[gn * 2 + 1];
            v = fmaxf(fmaf(f0, W1[j], fmaf(f1, W1[64 + j], b1[j])), 0.f);
        }
        sh1[idx] = v;
    }
    __syncthreads();
    for (int idx = t; idx < 4096; idx += 256) {
        int n = idx >> 6, k = idx & 63;
        int gn = n0 + n;
        if (gn >= N) continue;
        float acc = b2[k];
        const float* hrow = &sh1[n * 64];
        #pragma unroll 8
        for (int j = 0; j < 64; ++j) acc = fmaf(hrow[j], sW2[j * 64 + k], acc);
        out[gn * 64 + k] = acc;
    }
}

// ---------------------------------------------------------------------------
// Interval tables for the scalar-input edge MLP (exact algebra), all 8
// (layer,dir) configs in one launch. cfg<4: lv layer cfg; cfg>=4: lc layer-4.
// PQ interleaved: PQ8[cfg][(iv*64+k)*2]=P, +1=Q;  h_k(e)=relu(e*P+Q), iv=#{T<e}
// ---------------------------------------------------------------------------
__global__ __launch_bounds__(256) void build_tables_all_kernel(
    const float* __restrict__ lv_eW1, const float* __restrict__ lv_eb1,
    const float* __restrict__ lv_eW2, const float* __restrict__ lv_eb2,
    const float* __restrict__ lc_eW1, const float* __restrict__ lc_eb1,
    const float* __restrict__ lc_eW2, const float* __restrict__ lc_eb2,
    float* __restrict__ PQ8, float* __restrict__ sortedT8)
{
    const int cfg = blockIdx.x;
    const int li = (cfg < 4) ? cfg : cfg - 4;
    const float* eW1 = ((cfg < 4) ? lv_eW1 : lc_eW1) + li * 64;
    const float* eb1 = ((cfg < 4) ? lv_eb1 : lc_eb1) + li * 64;
    const float* eW2 = ((cfg < 4) ? lv_eW2 : lc_eW2) + li * 4096;
    const float* eb2 = ((cfg < 4) ? lv_eb2 : lc_eb2) + li * 64;
    float* PQ = PQ8 + cfg * 65 * 128;
    float* sortedT = sortedT8 + cfg * 64;

    __shared__ float sa[64], sb[64], sT[64];
    __shared__ int srank[64];
    const int t = threadIdx.x;
    if (t < 64) {
        float a = eW1[t], b = eb1[t];
        sa[t] = a; sb[t] = b;
        sT[t] = (a != 0.f) ? (-b / a) : INFINITY;
    }
    __syncthreads();
    if (t < 64) {
        float Tj = sT[t];
        int r = 0;
        for (int i = 0; i < 64; ++i) {
            float Ti = sT[i];
            r += (Ti < Tj || (Ti == Tj && i < t)) ? 1 : 0;   // stable rank
        }
        srank[t] = r;
        sortedT[r] = Tj;
    }
    __syncthreads();
    for (int idx = t; idx < 65 * 64; idx += 256) {
        int iv = idx >> 6, k = idx & 63;
        float accP = 0.f, accQ = 0.f;
        for (int j = 0; j < 64; ++j) {
            float a = sa[j];
            bool act = (a > 0.f) ? (srank[j] < iv)
                                 : ((a < 0.f) ? (srank[j] >= iv) : (sb[j] > 0.f));
            if (act) {
                float w = eW2[j * 64 + k];
                accP = fmaf(a, w, accP);
                accQ = fmaf(sb[j], w, accQ);
            }
        }
        PQ[idx * 2 + 0] = accP;
        PQ[idx * 2 + 1] = accQ + eb2[k];
    }
}

__device__ __forceinline__ int interval_of(const float* sT, float ev)
{
    int iv = 0;
    #pragma unroll
    for (int s = 32; s >= 1; s >>= 1)
        if (iv + s <= 64 && sT[iv + s - 1] < ev) iv += s;
    return iv;
}

// ---------------------------------------------------------------------------
// BN stats for all 8 configs, double accumulation, deterministic staging.
// grid = (NSB, 8)
// ---------------------------------------------------------------------------
__global__ __launch_bounds__(256) void edge_stats_all_kernel(
    const float* __restrict__ efv, const float* __restrict__ efc, int Ev, int Ec,
    const float* __restrict__ PQ8, const float* __restrict__ sortedT8,
    double* __restrict__ stage, int NSB)
{
    const int cfg = blockIdx.y;
    const float* ef = (cfg < 4) ? efv : efc;
    const int E = (cfg < 4) ? Ev : Ec;
    const float* PQ = PQ8 + cfg * 65 * 128;
    const float* sortedT = sortedT8 + cfg * 64;

    __shared__ float sPQ[65 * 128];
    __shared__ float sT[64];
    __shared__ double sred[2][4][64];
    const int t = threadIdx.x;
    for (int i = t; i < 65 * 128; i += 256) sPQ[i] = PQ[i];
    if (t < 64) sT[t] = sortedT[t];
    __syncthreads();
    const int lane = t & 63, wave = t >> 6;
    const int gw = blockIdx.x * 4 + wave;
    const int nW = NSB * 4;
    double sum = 0.0, sq = 0.0;
    const int nTiles = (E + 63) >> 6;
    for (int tile = gw; tile < nTiles; tile += nW) {
        const int p = tile << 6;
        const int m = min(64, E - p);
        float ev = 0.f; int iv = 0;
        if (lane < m) {
            ev = ef[p + lane];
            iv = interval_of(sT, ev);
        }
        #pragma unroll 8
        for (int k = 0; k < m; ++k) {
            float sev = readlane_f(ev, k);
            int siv = __builtin_amdgcn_readlane(iv, k);
            float2 pq = *reinterpret_cast<const float2*>(&sPQ[(siv * 64 + lane) * 2]);
            float h = fmaxf(fmaf(sev, pq.x, pq.y), 0.f);
            sum += (double)h;
            sq = fma((double)h, (double)h, sq);
        }
    }
    sred[0][wave][lane] = sum;
    sred[1][wave][lane] = sq;
    __syncthreads();
    if (t < 128) {
        int s = t >> 6, k = t & 63;
        double v = sred[s][0][k] + sred[s][1][k] + sred[s][2][k] + sred[s][3][k];
        stage[((size_t)(cfg * NSB + blockIdx.x) * 2 + s) * 64 + k] = v;
    }
}

__global__ __launch_bounds__(128) void bn_finalize_all_kernel(
    const double* __restrict__ stage, int NSB,
    const float* __restrict__ lv_g, const float* __restrict__ lv_bt,
    const float* __restrict__ lc_g, const float* __restrict__ lc_bt,
    int Ev, int Ec, float* __restrict__ stv)
{
    const int cfg = blockIdx.x;
    const int t = threadIdx.x;
    const int s = t >> 6, k = t & 63;
    double a = 0.0;
    for (int b = 0; b < NSB; ++b)
        a += stage[((size_t)(cfg * NSB + b) * 2 + s) * 64 + k];
    __shared__ double sh[2][64];
    sh[s][k] = a;
    __syncthreads();
    if (t < 64) {
        double En = (double)((cfg < 4) ? Ev : Ec);
        double mu = sh[0][k] / En;
        double var = sh[1][k] / En - mu * mu;
        if (var < 0.0) var = 0.0;
        const int li = (cfg < 4) ? cfg : cfg - 4;
        const float* g  = ((cfg < 4) ? lv_g  : lc_g)  + li * 64;
        const float* bt = ((cfg < 4) ? lv_bt : lc_bt) + li * 64;
        double sc = (double)g[k] / sqrt(var + 1e-5);
        stv[cfg * 128 + k] = (float)sc;
        stv[cfg * 128 + 64 + k] = (float)((double)bt[k] - mu * sc);
    }
}

// ---------------------------------------------------------------------------
// CSR build: count -> scan(3 kernels, produces rowptr + working cursor)
//           -> scatter-permute (efp, srcp only; targets implied by rowptr)
// ---------------------------------------------------------------------------
__global__ void count_kernel(const int* __restrict__ tgt_idx,
                             int* __restrict__ cnt, int E)
{
    int i = blockIdx.x * blockDim.x + threadIdx.x;
    if (i < E) atomicAdd(&cnt[tgt_idx[i]], 1);
}

__global__ __launch_bounds__(256) void scan1_kernel(const int* __restrict__ cnt,
                                                    int* __restrict__ bsum, int N)
{
    __shared__ int sred[256];
    const int b = blockIdx.x, t = threadIdx.x;
    const int base = b * 1024;
    int s = 0;
    for (int i = t; i < 1024; i += 256) {
        int g = base + i;
        s += (g < N) ? cnt[g] : 0;
    }
    sred[t] = s; __syncthreads();
    for (int o = 128; o > 0; o >>= 1) {
        if (t < o) sred[t] += sred[t + o];
        __syncthreads();
    }
    if (t == 0) bsum[b] = sred[0];
}

__global__ __launch_bounds__(1024) void scan2_kernel(int* __restrict__ bsum, int G,
                                                     int* __restrict__ rowptr_last, int E)
{
    __shared__ int s[1024];
    const int t = threadIdx.x;
    int v = (t < G) ? bsum[t] : 0;
    s[t] = v; __syncthreads();
    for (int o = 1; o < 1024; o <<= 1) {
        int x = (t >= o) ? s[t - o] : 0;
        __syncthreads();
        s[t] += x;
        __syncthreads();
    }
    if (t < G) bsum[t] = s[t] - v;   // exclusive
    if (t == 0) *rowptr_last = E;    // rowptr[N] = E
}

__global__ __launch_bounds__(256) void scan3_kernel(const int* __restrict__ cnt,
                                                    const int* __restrict__ bsum,
                                                    int* __restrict__ rowptr,
                                                    int* __restrict__ cursor, int N)
{
    __shared__ int sthr[256];
    const int b = blockIdx.x, t = threadIdx.x;
    const int base = b * 1024 + t * 4;
    int loc[4]; int run = 0;
    #pragma unroll
    for (int j = 0; j < 4; ++j) {
        int g = base + j;
        int c = (g < N) ? cnt[g] : 0;
        loc[j] = run; run += c;
    }
    sthr[t] = run; __syncthreads();
    int own = run;
    for (int o = 1; o < 256; o <<= 1) {
        int x = (t >= o) ? sthr[t - o] : 0;
        __syncthreads();
        sthr[t] += x;
        __syncthreads();
    }
    int ex = sthr[t] - own + bsum[b];
    #pragma unroll
    for (int j = 0; j < 4; ++j) {
        int g = base + j;
        if (g < N) { rowptr[g] = ex + loc[j]; cursor[g] = ex + loc[j]; }
    }
}

__global__ void scatter_kernel(const float* __restrict__ ef, const int* __restrict__ ei,
                               int* __restrict__ cursor, float* __restrict__ efp,
                               int* __restrict__ srcp, int E)
{
    int e = blockIdx.x * blockDim.x + threadIdx.x;
    if (e < E) {
        int tg = ei[E + e];
        int pos = atomicAdd(&cursor[tg], 1);
        efp[pos] = ef[e];
        srcp[pos] = ei[e];
    }
}

// ---------------------------------------------------------------------------
// Fused bipartite layer. Block owns 64 consecutive TARGET nodes = contiguous
// CSR edge range. Phase A: per-edge msg = relu(src + bn(h(ef))), mean-
// aggregated into LDS (atomics only at row boundaries). Phase B: combine
// matmuls + L2-normalize + relu, in-place tgt update. Phase C (FUSE_ACC):
// acc += newTgt @ accW (lin1 block).  Requires N < 2^18 (src id packing).
// ---------------------------------------------------------------------------
template <bool FUSE_ACC>
__global__ __launch_bounds__(256) void layer_kernel(
    const float* __restrict__ efp, const int* __restrict__ srcp,
    const int* __restrict__ rowptr, const float* __restrict__ src,
    float* __restrict__ tgt,
    const float* __restrict__ PQ, const float* __restrict__ sortedT,
    const float* __restrict__ st,
    const float* __restrict__ lW, const float* __restrict__ lb,
    const float* __restrict__ rW,
    const float* __restrict__ accW, float* __restrict__ acc, int N)
{
    __shared__ float sU[65 * 128];      // A: PQ tables | B: lW(0..4095), rW(4096..8191) | C: accW
    __shared__ float sAgg[64][65];      // A: mean-agg accumulator | B-out: staged outputs
    __shared__ float sTg[64][65];       // B: old tgt | C: new tgt
    __shared__ float sT[64];
    __shared__ int   sRp[65];
    __shared__ float part[4][64];
    __shared__ float srn[64];

    const int t = threadIdx.x, lane = t & 63, wave = t >> 6;
    const int n0 = blockIdx.x * 64;

    for (int i = t; i < 64 * 65; i += 256) (&sAgg[0][0])[i] = 0.f;
    for (int i = t; i < 65 * 128; i += 256) sU[i] = PQ[i];
    if (t < 64) sT[t] = sortedT[t];
    if (t < 65) sRp[t] = rowptr[min(n0 + t, N)];
    __syncthreads();

    const float ssv = st[lane], ttv = st[64 + lane];
    const int e0 = sRp[0], e1 = sRp[64];
    float racc = 0.f;
    for (int tb = e0 + wave * 64; tb < e1; tb += 256) {
        const int m = min(64, e1 - tb);
        float ev = 0.f; unsigned pk = 0;
        if (lane < m) {
            int g = tb + lane;
            ev = efp[g];
            unsigned is = (unsigned)srcp[g];
            int lo = 0;                         // binary ascent: sRp[lo] <= g < sRp[lo+1]
            #pragma unroll
            for (int s = 32; s >= 1; s >>= 1) {
                int c = lo + s;
                if (c <= 63 && sRp[c] <= g) lo = c;
            }
            unsigned bnd = (g + 1 == sRp[lo + 1]) ? 1u : 0u;
            unsigned iv = (unsigned)interval_of(sT, ev);
            pk = is | (iv << 18) | ((unsigned)lo << 25) | (bnd << 31);
        }
        #pragma unroll 8
        for (int k = 0; k < m; ++k) {
            float sev = readlane_f(ev, k);
            unsigned spk = readlane_u(pk, k);
            int sis = (int)(spk & 0x3FFFFu);
            int siv = (int)((spk >> 18) & 0x7Fu);
            float2 pq = *reinterpret_cast<const float2*>(&sU[(siv * 64 + lane) * 2]);
            float h = fmaxf(fmaf(sev, pq.x, pq.y), 0.f);
            float msg = fmaxf(src[(size_t)sis * 64 + lane] + fmaf(h, ssv, ttv), 0.f);
            racc += msg;
            if (spk >> 31) {                    // row end (wave-uniform branch)
                int l = (int)((spk >> 25) & 63u);
                float inv = 1.f / (float)(sRp[l + 1] - sRp[l]);
                atomicAdd(&sAgg[l][lane], racc * inv);
                racc = 0.f;
            }
        }
        if (racc != 0.f) {                      // tile ended mid-row: flush partial
            unsigned spk = readlane_u(pk, m - 1);
            int l = (int)((spk >> 25) & 63u);
            float inv = 1.f / (float)(sRp[l + 1] - sRp[l]);
            atomicAdd(&sAgg[l][lane], racc * inv);
            racc = 0.f;
        }
    }
    __syncthreads();
    // ---- phase B: combine ----
    float* sLW = sU; float* sRW = sU + 4096;
    for (int idx = t; idx < 4096; idx += 256) { sLW[idx] = lW[idx]; sRW[idx] = rW[idx]; }
    for (int idx = t; idx < 4096; idx += 256) {
        int n = idx >> 6, j = idx & 63;
        int gn = n0 + n;
        sTg[n][j] = (gn < N) ? tgt[(size_t)gn * 64 + j] : 0.f;
    }
    __syncthreads();
    const int n = lane;
    const float* mr = sAgg[n];
    const float* tr = sTg[n];
    float o[16]; float ssq = 0.f;
    for (int m4 = 0; m4 < 4; ++m4) {
        const int kb = (wave + m4 * 4) * 4;
        float o0 = 0, o1 = 0, o2 = 0, o3 = 0;
        #pragma unroll 8
        for (int j = 0; j < 64; ++j) {
            float mv = mr[j];
            float4 w4 = *reinterpret_cast<const float4*>(&sLW[j * 64 + kb]);
            o0 = fmaf(mv, w4.x, o0); o1 = fmaf(mv, w4.y, o1);
            o2 = fmaf(mv, w4.z, o2); o3 = fmaf(mv, w4.w, o3);
        }
        #pragma unroll 8
        for (int j = 0; j < 64; ++j) {
            float tv = tr[j];
            float4 w4 = *reinterpret_cast<const float4*>(&sRW[j * 64 + kb]);
            o0 = fmaf(tv, w4.x, o0); o1 = fmaf(tv, w4.y, o1);
            o2 = fmaf(tv, w4.z, o2); o3 = fmaf(tv, w4.w, o3);
        }
        o0 += lb[kb + 0]; o1 += lb[kb + 1]; o2 += lb[kb + 2]; o3 += lb[kb + 3];
        o[m4 * 4 + 0] = o0; o[m4 * 4 + 1] = o1; o[m4 * 4 + 2] = o2; o[m4 * 4 + 3] = o3;
        ssq = fmaf(o0, o0, fmaf(o1, o1, fmaf(o2, o2, fmaf(o3, o3, ssq))));
    }
    part[wave][n] = ssq;
    __syncthreads();
    if (t < 64) {
        float s = part[0][t] + part[1][t] + part[2][t] + part[3][t];
        srn[t] = 1.f / fmaxf(sqrtf(s), 1e-12f);
    }
    for (int m4 = 0; m4 < 4; ++m4) {            // stage outputs (sAgg reads done)
        const int kb = (wave + m4 * 4) * 4;
        sAgg[n][kb + 0] = o[m4 * 4 + 0];
        sAgg[n][kb + 1] = o[m4 * 4 + 1];
        sAgg[n][kb + 2] = o[m4 * 4 + 2];
        sAgg[n][kb + 3] = o[m4 * 4 + 3];
    }
    __syncthreads();
    for (int idx = t; idx < 4096; idx += 256) {
        int nn = idx >> 6, k = idx & 63;
        int gn = n0 + nn;
        float v = fmaxf(sAgg[nn][k] * srn[nn], 0.f);
        if (FUSE_ACC) sTg[nn][k] = v;
        if (gn < N) tgt[(size_t)gn * 64 + k] = v;
    }
    if (FUSE_ACC) {
        __syncthreads();
        for (int idx = t; idx < 4096; idx += 256) sU[idx] = accW[idx];
        __syncthreads();
        const float* xr = sTg[n];
        const int gn = n0 + n;
        for (int m4 = 0; m4 < 4; ++m4) {
            const int kb = (wave + m4 * 4) * 4;
            float o0 = 0, o1 = 0, o2 = 0, o3 = 0;
            #pragma unroll 8
            for (int j = 0; j < 64; ++j) {
                float xv = xr[j];
                float4 w4 = *reinterpret_cast<const float4*>(&sU[j * 64 + kb]);
                o0 = fmaf(xv, w4.x, o0); o1 = fmaf(xv, w4.y, o1);
                o2 = fmaf(xv, w4.z, o2); o3 = fmaf(xv, w4.w, o3);
            }
            if (gn < N) {
                float4* ap = reinterpret_cast<float4*>(&acc[(size_t)gn * 64 + kb]);
                float4 old = *ap;
                *ap = make_float4(old.x + o0, old.y + o1, old.z + o2, old.w + o3);
            }
        }
    }
}

// ---------------------------------------------------------------------------
// acc = X @ W   (initial lin1 block, x_var[0])
// ---------------------------------------------------------------------------
__global__ __launch_bounds__(256) void acc_gemm_init_kernel(
    const float* __restrict__ X, const float* __restrict__ W,
    float* __restrict__ acc, int N)
{
    __shared__ float sW[64 * 64];
    __shared__ float sX[64][65];
    const int n0 = blockIdx.x * 64;
    const int t = threadIdx.x;
    for (int idx = t; idx < 4096; idx += 256) sW[idx] = W[idx];
    for (int idx = t; idx < 4096; idx += 256) {
        int n = idx >> 6, j = idx & 63;
        int gn = n0 + n;
        sX[n][j] = (gn < N) ? X[gn * 64 + j] : 0.f;
    }
    __syncthreads();
    const int n = t & 63;
    const int gn = n0 + n;
    for (int m4 = 0; m4 < 4; ++m4) {
        int kb = ((t >> 6) + m4 * 4) * 4;
        float o0 = 0, o1 = 0, o2 = 0, o3 = 0;
        const float* xr = sX[n];
        #pragma unroll 8
        for (int j = 0; j < 64; ++j) {
            float xv = xr[j];
            float4 w4 = *reinterpret_cast<const float4*>(&sW[j * 64 + kb]);
            o0 = fmaf(xv, w4.x, o0); o1 = fmaf(xv, w4.y, o1);
            o2 = fmaf(xv, w4.z, o2); o3 = fmaf(xv, w4.w, o3);
        }
        if (gn < N)
            *reinterpret_cast<float4*>(&acc[(size_t)gn * 64 + kb]) =
                make_float4(o0, o1, o2, o3);
    }
}

// ---------------------------------------------------------------------------
// final head: relu(acc+b1) -> relu(@W2+b2) -> relu(@W3+b3) -> @W4+b4 -> logsoftmax
// ---------------------------------------------------------------------------
__global__ __launch_bounds__(256) void final_kernel(
    const float* __restrict__ acc, const float* __restrict__ b1,
    const float* __restrict__ W2, const float* __restrict__ b2,
    const float* __restrict__ W3, const float* __restrict__ b3,
    const float* __restrict__ W4, const float* __restrict__ b4,
    float* __restrict__ out, int N)
{
    __shared__ float sW[64 * 64];
    __shared__ float sA[64][65], sB[64][65];
    __shared__ float sy[64][2];
    const int n0 = blockIdx.x * 64;
    const int t = threadIdx.x;
    for (int idx = t; idx < 4096; idx += 256) sW[idx] = W2[idx];
    for (int idx = t; idx < 4096; idx += 256) {
        int n = idx >> 6, j = idx & 63;
        int gn = n0 + n;
        sA[n][j] = (gn < N) ? fmaxf(acc[gn * 64 + j] + b1[j], 0.f) : 0.f;
    }
    __syncthreads();
    const int n = t & 63;
    for (int m4 = 0; m4 < 4; ++m4) {
        int kb = ((t >> 6) + m4 * 4) * 4;
        float o0 = 0, o1 = 0, o2 = 0, o3 = 0;
        const float* xr = sA[n];
        #pragma unroll 8
        for (int j = 0; j < 64; ++j) {
            float xv = xr[j];
            float4 w4 = *reinterpret_cast<const float4*>(&sW[j * 64 + kb]);
            o0 = fmaf(xv, w4.x, o0); o1 = fmaf(xv, w4.y, o1);
            o2 = fmaf(xv, w4.z, o2); o3 = fmaf(xv, w4.w, o3);
        }
        sB[n][kb + 0] = fmaxf(o0 + b2[kb + 0], 0.f);
        sB[n][kb + 1] = fmaxf(o1 + b2[kb + 1], 0.f);
        sB[n][kb + 2] = fmaxf(o2 + b2[kb + 2], 0.f);
        sB[n][kb + 3] = fmaxf(o3 + b2[kb + 3], 0.f);
    }
    __syncthreads();
    for (int idx = t; idx < 4096; idx += 256) sW[idx] = W3[idx];
    __syncthreads();
    for (int m4 = 0; m4 < 4; ++m4) {
        int kb = ((t >> 6) + m4 * 4) * 4;
        float o0 = 0, o1 = 0, o2 = 0, o3 = 0;
        const float* xr = sB[n];
        #pragma unroll 8
        for (int j = 0; j < 64; ++j) {
            float xv = xr[j];
            float4 w4 = *reinterpret_cast<const float4*>(&sW[j * 64 + kb]);
            o0 = fmaf(xv, w4.x, o0); o1 = fmaf(xv, w4.y, o1);
            o2 = fmaf(xv, w4.z, o2); o3 = fmaf(xv, w4.w, o3);
        }
        sA[n][kb + 0] = fmaxf(o0 + b3[kb + 0], 0.f);
        sA[n][kb + 1] = fmaxf(o1 + b3[kb + 1], 0.f);
        sA[n][kb + 2] = fmaxf(o2 + b3[kb + 2], 0.f);
        sA[n][kb + 3] = fmaxf(o3 + b3[kb + 3], 0.f);
    }
    __syncthreads();
    if (t < 128) {
        int nn = t >> 1, c = t & 1;
        float a = b4[c];
        for (int j = 0; j < 64; ++j) a = fmaf(sA[nn][j], W4[j * 2 + c], a);
        sy[nn][c] = a;
    }
    __syncthreads();
    if (t < 64) {
        int gn = n0 + t;
        if (gn < N) {
            float y0 = sy[t][0], y1 = sy[t][1];
            float m = fmaxf(y0, y1);
            float lse = m + logf(expf(y0 - m) + expf(y1 - m));
            out[gn * 2 + 0] = y0 - lse;
            out[gn * 2 + 1] = y1 - lse;
        }
    }
}

// ---------------------------------------------------------------------------
extern "C" void kernel_launch(void* const* d_in, const int* in_sizes, int n_in,
                              void* d_out, int out_size, void* d_ws, size_t ws_size,
                              hipStream_t stream)
{
    const float* varf    = (const float*)d_in[0];
    const float* conf    = (const float*)d_in[1];
    const float* ev_feat = (const float*)d_in[2];
    const float* ec_feat = (const float*)d_in[3];
    const int*   ei_var  = (const int*)d_in[4];
    const int*   ei_con  = (const int*)d_in[5];
    const float* enc_v_W1 = (const float*)d_in[6];
    const float* enc_v_b1 = (const float*)d_in[7];
    const float* enc_v_W2 = (const float*)d_in[8];
    const float* enc_v_b2 = (const float*)d_in[9];
    const float* enc_c_W1 = (const float*)d_in[10];
    const float* enc_c_b1 = (const float*)d_in[11];
    const float* enc_c_W2 = (const float*)d_in[12];
    const float* enc_c_b2 = (const float*)d_in[13];
    const float* lv_eW1 = (const float*)d_in[14];
    const float* lv_eb1 = (const float*)d_in[15];
    const float* lv_eW2 = (const float*)d_in[16];
    const float* lv_eb2 = (const float*)d_in[17];
    const float* lv_g   = (const float*)d_in[18];
    const float* lv_bt  = (const float*)d_in[19];
    const float* lv_lW  = (const float*)d_in[20];
    const float* lv_lb  = (const float*)d_in[21];
    const float* lv_rW  = (const float*)d_in[22];
    const float* lc_eW1 = (const float*)d_in[23];
    const float* lc_eb1 = (const float*)d_in[24];
    const float* lc_eW2 = (const float*)d_in[25];
    const float* lc_eb2 = (const float*)d_in[26];
    const float* lc_g   = (const float*)d_in[27];
    const float* lc_bt  = (const float*)d_in[28];
    const float* lc_lW  = (const float*)d_in[29];
    const float* lc_lb  = (const float*)d_in[30];
    const float* lc_rW  = (const float*)d_in[31];
    const float* lin1_W = (const float*)d_in[32];
    const float* lin1_b = (const float*)d_in[33];
    const float* lin2_W = (const float*)d_in[34];
    const float* lin2_b = (const float*)d_in[35];
    const float* lin3_W = (const float*)d_in[36];
    const float* lin3_b = (const float*)d_in[37];
    const float* lin4_W = (const float*)d_in[38];
    const float* lin4_b = (const float*)d_in[39];

    const int Nv = in_sizes[0] / 2, Nc = in_sizes[1] / 2;
    const int Ev = in_sizes[2], Ec = in_sizes[3];
    const int maxN = (Nv > Nc) ? Nv : Nc;
    const int NSB = 128;   // stats blocks per config

    // ---- workspace budget check (total ~99.7 MB at nominal sizes) ----
    size_t need = (size_t)(8 * NSB * 2 * 64) * 8;                      // stage (doubles)
    need += ((size_t)Nv * 64 * 2 + (size_t)Nc * 64) * 4;               // xv, acc, xc
    need += (size_t)(8 * 65 * 128 + 8 * 64 + 8 * 128) * 4;             // PQ8, sortedT8, stv
    need += ((size_t)Ev * 2 + (size_t)Ec * 2) * 4;                     // efp+srcp, both graphs
    need += ((size_t)Nc + 1 + (size_t)Nv + 1) * 4;                     // rowptrs
    need += ((size_t)maxN * 2 + 1024) * 4;                             // cnt, cursor, bsum
    if (ws_size < need) {   // clean visible failure instead of container-killing OOB
        hipMemsetAsync(d_out, 0, (size_t)out_size * sizeof(float), stream);
        return;
    }

    double* stage = (double*)d_ws;
    float* ws = (float*)(stage + (size_t)8 * NSB * 2 * 64);
    float* xv  = ws;  ws += (size_t)Nv * 64;
    float* xc  = ws;  ws += (size_t)Nc * 64;
    float* acc = ws;  ws += (size_t)Nv * 64;
    float* PQ8 = ws;      ws += 8 * 65 * 128;
    float* sortedT8 = ws; ws += 8 * 64;
    float* stv = ws;      ws += 8 * 128;
    float* efp_v = ws;            ws += Ev;
    int*   srcp_v = (int*)ws;     ws += Ev;
    float* efp_c = ws;            ws += Ec;
    int*   srcp_c = (int*)ws;     ws += Ec;
    int*   rowptr_v = (int*)ws;   ws += Nc + 1;
    int*   rowptr_c = (int*)ws;   ws += Nv + 1;
    int*   cnt    = (int*)ws;     ws += maxN;
    int*   cursor = (int*)ws;     ws += maxN;
    int*   bsum   = (int*)ws;     ws += 1024;

    const dim3 blk(256);
    const int gbV = (Nv + 63) / 64, gbC = (Nc + 63) / 64;

    enc_kernel<<<gbV, blk, 0, stream>>>(varf, enc_v_W1, enc_v_b1, enc_v_W2, enc_v_b2, xv, Nv);
    enc_kernel<<<gbC, blk, 0, stream>>>(conf, enc_c_W1, enc_c_b1, enc_c_W2, enc_c_b2, xc, Nc);

    // ---- CSR build: var-graph (targets = con), con-graph (targets = var) ----
    {
        hipMemsetAsync(cnt, 0, (size_t)Nc * sizeof(int), stream);
        count_kernel<<<(Ev + 255) / 256, blk, 0, stream>>>(ei_var + Ev, cnt, Ev);
        int G = (Nc + 1023) / 1024;
        scan1_kernel<<<G, blk, 0, stream>>>(cnt, bsum, Nc);
        scan2_kernel<<<1, 1024, 0, stream>>>(bsum, G, rowptr_v + Nc, Ev);
        scan3_kernel<<<G, blk, 0, stream>>>(cnt, bsum, rowptr_v, cursor, Nc);
        scatter_kernel<<<(Ev + 255) / 256, blk, 0, stream>>>(ev_feat, ei_var, cursor,
                                                             efp_v, srcp_v, Ev);
        hipMemsetAsync(cnt, 0, (size_t)Nv * sizeof(int), stream);
        count_kernel<<<(Ec + 255) / 256, blk, 0, stream>>>(ei_con + Ec, cnt, Ec);
        G = (Nv + 1023) / 1024;
        scan1_kernel<<<G, blk, 0, stream>>>(cnt, bsum, Nv);
        scan2_kernel<<<1, 1024, 0, stream>>>(bsum, G, rowptr_c + Nv, Ec);
        scan3_kernel<<<G, blk, 0, stream>>>(cnt, bsum, rowptr_c, cursor, Nv);
        scatter_kernel<<<(Ec + 255) / 256, blk, 0, stream>>>(ec_feat, ei_con, cursor,
                                                             efp_c, srcp_c, Ec);
    }

    // ---- all 8 configs' edge-MLP tables + BN stats, batched upfront ----
    build_tables_all_kernel<<<8, blk, 0, stream>>>(
        lv_eW1, lv_eb1, lv_eW2, lv_eb2, lc_eW1, lc_eb1, lc_eW2, lc_eb2, PQ8, sortedT8);
    edge_stats_all_kernel<<<dim3(NSB, 8), blk, 0, stream>>>(
        ev_feat, ec_feat, Ev, Ec, PQ8, sortedT8, stage, NSB);
    bn_finalize_all_kernel<<<8, 128, 0, stream>>>(
        stage, NSB, lv_g, lv_bt, lc_g, lc_bt, Ev, Ec, stv);

    acc_gemm_init_kernel<<<gbV, blk, 0, stream>>>(xv, lin1_W, acc, Nv);

    for (int i = 0; i < 4; ++i) {
        // var -> con  (cfg = i): update xc from xv
        layer_kernel<false><<<gbC, blk, 0, stream>>>(
            efp_v, srcp_v, rowptr_v, xv, xc,
            PQ8 + i * 65 * 128, sortedT8 + i * 64, stv + i * 128,
            lv_lW + i * 4096, lv_lb + i * 64, lv_rW + i * 4096,
            nullptr, nullptr, Nc);
        // con -> var  (cfg = 4+i): update xv from xc, fuse acc += xv_new @ lin1_blk
        layer_kernel<true><<<gbV, blk, 0, stream>>>(
            efp_c, srcp_c, rowptr_c, xc, xv,
            PQ8 + (4 + i) * 65 * 128, sortedT8 + (4 + i) * 64, stv + (4 + i) * 128,
            lc_lW + i * 4096, lc_lb + i * 64, lc_rW + i * 4096,
            lin1_W + (i + 1) * 4096, acc, Nv);
    }

    final_kernel<<<gbV, blk, 0, stream>>>(acc, lin1_b, lin2_W, lin2_b,
                                          lin3_W, lin3_b, lin4_W, lin4_b,
                                          (float*)d_out, Nv);
}

// Round 5
// 2146.210 us; speedup vs baseline: 3.1239x; 1.8177x over previous
//
#include <hip/hip_runtime.h>
#include <math.h>

__device__ __forceinline__ float readlane_f(float v, int l) {
    return __int_as_float(__builtin_amdgcn_readlane(__float_as_int(v), l));
}
__device__ __forceinline__ unsigned readlane_u(unsigned v, int l) {
    return (unsigned)__builtin_amdgcn_readlane((int)v, l);
}

// ---------------------------------------------------------------------------
// Node encoder: out = relu(feat @ W1 + b1) @ W2 + b2,  feat [N,2]
// ---------------------------------------------------------------------------
__global__ __launch_bounds__(256) void enc_kernel(
    const float* __restrict__ feat, const float* __restrict__ W1,
    const float* __restrict__ b1, const float* __restrict__ W2,
    const float* __restrict__ b2, float* __restrict__ out, int N)
{
    __shared__ float sW2[64 * 64];
    __shared__ float sh1[64 * 64];
    const int n0 = blockIdx.x * 64;
    const int t = threadIdx.x;
    for (int idx = t; idx < 4096; idx += 256) sW2[idx] = W2[idx];
    for (int idx = t; idx < 4096; idx += 256) {
        int n = idx >> 6, j = idx & 63;
        int gn = n0 + n;
        float v = 0.f;
        if (gn < N) {
            float f0 = feat[gn * 2 + 0], f1 = feat[gn * 2 + 1];
            v = fmaxf(fmaf(f0, W1[j], fmaf(f1, W1[64 + j], b1[j])), 0.f);
        }
        sh1[idx] = v;
    }
    __syncthreads();
    for (int idx = t; idx < 4096; idx += 256) {
        int n = idx >> 6, k = idx & 63;
        int gn = n0 + n;
        if (gn >= N) continue;
        float acc = b2[k];
        const float* hrow = &sh1[n * 64];
        #pragma unroll 8
        for (int j = 0; j < 64; ++j) acc = fmaf(hrow[j], sW2[j * 64 + k], acc);
        out[gn * 64 + k] = acc;
    }
}

// ---------------------------------------------------------------------------
// Interval tables for the scalar-input edge MLP (exact algebra), all 8
// (layer,dir) configs in one launch. cfg<4: lv layer cfg; cfg>=4: lc layer-4.
// PQ interleaved: PQ8[cfg][(iv*64+k)*2]=P, +1=Q;  h_k(e)=relu(e*P+Q), iv=#{T<e}
// ---------------------------------------------------------------------------
__global__ __launch_bounds__(256) void build_tables_all_kernel(
    const float* __restrict__ lv_eW1, const float* __restrict__ lv_eb1,
    const float* __restrict__ lv_eW2, const float* __restrict__ lv_eb2,
    const float* __restrict__ lc_eW1, const float* __restrict__ lc_eb1,
    const float* __restrict__ lc_eW2, const float* __restrict__ lc_eb2,
    float* __restrict__ PQ8, float* __restrict__ sortedT8)
{
    const int cfg = blockIdx.x;
    const int li = (cfg < 4) ? cfg : cfg - 4;
    const float* eW1 = ((cfg < 4) ? lv_eW1 : lc_eW1) + li * 64;
    const float* eb1 = ((cfg < 4) ? lv_eb1 : lc_eb1) + li * 64;
    const float* eW2 = ((cfg < 4) ? lv_eW2 : lc_eW2) + li * 4096;
    const float* eb2 = ((cfg < 4) ? lv_eb2 : lc_eb2) + li * 64;
    float* PQ = PQ8 + cfg * 65 * 128;
    float* sortedT = sortedT8 + cfg * 64;

    __shared__ float sa[64], sb[64], sT[64];
    __shared__ int srank[64];
    const int t = threadIdx.x;
    if (t < 64) {
        float a = eW1[t], b = eb1[t];
        sa[t] = a; sb[t] = b;
        sT[t] = (a != 0.f) ? (-b / a) : INFINITY;
    }
    __syncthreads();
    if (t < 64) {
        float Tj = sT[t];
        int r = 0;
        for (int i = 0; i < 64; ++i) {
            float Ti = sT[i];
            r += (Ti < Tj || (Ti == Tj && i < t)) ? 1 : 0;   // stable rank
        }
        srank[t] = r;
        sortedT[r] = Tj;
    }
    __syncthreads();
    for (int idx = t; idx < 65 * 64; idx += 256) {
        int iv = idx >> 6, k = idx & 63;
        float accP = 0.f, accQ = 0.f;
        for (int j = 0; j < 64; ++j) {
            float a = sa[j];
            bool act = (a > 0.f) ? (srank[j] < iv)
                                 : ((a < 0.f) ? (srank[j] >= iv) : (sb[j] > 0.f));
            if (act) {
                float w = eW2[j * 64 + k];
                accP = fmaf(a, w, accP);
                accQ = fmaf(sb[j], w, accQ);
            }
        }
        PQ[idx * 2 + 0] = accP;
        PQ[idx * 2 + 1] = accQ + eb2[k];
    }
}

__device__ __forceinline__ int interval_of(const float* sT, float ev)
{
    int iv = 0;
    #pragma unroll
    for (int s = 32; s >= 1; s >>= 1)
        if (iv + s <= 64 && sT[iv + s - 1] < ev) iv += s;
    return iv;
}

// ---------------------------------------------------------------------------
// BN stats for all 8 configs, double accumulation, deterministic staging.
// PQ read from global (L1/L2-hot 33KB table); chunk-16 batched loads.
// grid = (NSB, 8)
// ---------------------------------------------------------------------------
__global__ __launch_bounds__(256) void edge_stats_all_kernel(
    const float* __restrict__ efv, const float* __restrict__ efc, int Ev, int Ec,
    const float* __restrict__ PQ8, const float* __restrict__ sortedT8,
    double* __restrict__ stage, int NSB)
{
    const int cfg = blockIdx.y;
    const float* ef = (cfg < 4) ? efv : efc;
    const int E = (cfg < 4) ? Ev : Ec;
    const float2* __restrict__ PQg = (const float2*)(PQ8 + cfg * 65 * 128);
    const float* sortedT = sortedT8 + cfg * 64;

    __shared__ float sT[64];
    __shared__ double sred[2][4][64];
    const int t = threadIdx.x;
    if (t < 64) sT[t] = sortedT[t];
    __syncthreads();
    const int lane = t & 63, wave = t >> 6;
    const int gw = blockIdx.x * 4 + wave;
    const int nW = NSB * 4;
    double sum = 0.0, sq = 0.0;
    const int nTiles = (E + 63) >> 6;
    for (int tile = gw; tile < nTiles; tile += nW) {
        const int p = tile << 6;
        const int m = min(64, E - p);
        float ev = 0.f; int iv = 0;
        if (lane < m) {
            ev = ef[p + lane];
            iv = interval_of(sT, ev);
        }
        for (int c = 0; c < m; c += 16) {
            if (c + 16 <= m) {
                float h[16];
                #pragma unroll
                for (int k = 0; k < 16; ++k) {
                    float sev = readlane_f(ev, c + k);
                    int siv = __builtin_amdgcn_readlane(iv, c + k);
                    float2 pq = PQg[siv * 64 + lane];
                    h[k] = fmaxf(fmaf(sev, pq.x, pq.y), 0.f);
                }
                #pragma unroll
                for (int k = 0; k < 16; ++k) {
                    sum += (double)h[k];
                    sq = fma((double)h[k], (double)h[k], sq);
                }
            } else {
                for (int k = c; k < m; ++k) {
                    float sev = readlane_f(ev, k);
                    int siv = __builtin_amdgcn_readlane(iv, k);
                    float2 pq = PQg[siv * 64 + lane];
                    float h = fmaxf(fmaf(sev, pq.x, pq.y), 0.f);
                    sum += (double)h;
                    sq = fma((double)h, (double)h, sq);
                }
            }
        }
    }
    sred[0][wave][lane] = sum;
    sred[1][wave][lane] = sq;
    __syncthreads();
    if (t < 128) {
        int s = t >> 6, k = t & 63;
        double v = sred[s][0][k] + sred[s][1][k] + sred[s][2][k] + sred[s][3][k];
        stage[((size_t)(cfg * NSB + blockIdx.x) * 2 + s) * 64 + k] = v;
    }
}

__global__ __launch_bounds__(128) void bn_finalize_all_kernel(
    const double* __restrict__ stage, int NSB,
    const float* __restrict__ lv_g, const float* __restrict__ lv_bt,
    const float* __restrict__ lc_g, const float* __restrict__ lc_bt,
    int Ev, int Ec, float* __restrict__ stv)
{
    const int cfg = blockIdx.x;
    const int t = threadIdx.x;
    const int s = t >> 6, k = t & 63;
    double a = 0.0;
    for (int b = 0; b < NSB; ++b)
        a += stage[((size_t)(cfg * NSB + b) * 2 + s) * 64 + k];
    __shared__ double sh[2][64];
    sh[s][k] = a;
    __syncthreads();
    if (t < 64) {
        double En = (double)((cfg < 4) ? Ev : Ec);
        double mu = sh[0][k] / En;
        double var = sh[1][k] / En - mu * mu;
        if (var < 0.0) var = 0.0;
        const int li = (cfg < 4) ? cfg : cfg - 4;
        const float* g  = ((cfg < 4) ? lv_g  : lc_g)  + li * 64;
        const float* bt = ((cfg < 4) ? lv_bt : lc_bt) + li * 64;
        double sc = (double)g[k] / sqrt(var + 1e-5);
        stv[cfg * 128 + k] = (float)sc;
        stv[cfg * 128 + 64 + k] = (float)((double)bt[k] - mu * sc);
    }
}

// ---------------------------------------------------------------------------
// CSR build: count -> scan(3 kernels, produces rowptr + working cursor)
//           -> scatter-permute (efp, srcp only; targets implied by rowptr)
// ---------------------------------------------------------------------------
__global__ void count_kernel(const int* __restrict__ tgt_idx,
                             int* __restrict__ cnt, int E)
{
    int i = blockIdx.x * blockDim.x + threadIdx.x;
    if (i < E) atomicAdd(&cnt[tgt_idx[i]], 1);
}

__global__ __launch_bounds__(256) void scan1_kernel(const int* __restrict__ cnt,
                                                    int* __restrict__ bsum, int N)
{
    __shared__ int sred[256];
    const int b = blockIdx.x, t = threadIdx.x;
    const int base = b * 1024;
    int s = 0;
    for (int i = t; i < 1024; i += 256) {
        int g = base + i;
        s += (g < N) ? cnt[g] : 0;
    }
    sred[t] = s; __syncthreads();
    for (int o = 128; o > 0; o >>= 1) {
        if (t < o) sred[t] += sred[t + o];
        __syncthreads();
    }
    if (t == 0) bsum[b] = sred[0];
}

__global__ __launch_bounds__(1024) void scan2_kernel(int* __restrict__ bsum, int G,
                                                     int* __restrict__ rowptr_last, int E)
{
    __shared__ int s[1024];
    const int t = threadIdx.x;
    int v = (t < G) ? bsum[t] : 0;
    s[t] = v; __syncthreads();
    for (int o = 1; o < 1024; o <<= 1) {
        int x = (t >= o) ? s[t - o] : 0;
        __syncthreads();
        s[t] += x;
        __syncthreads();
    }
    if (t < G) bsum[t] = s[t] - v;   // exclusive
    if (t == 0) *rowptr_last = E;    // rowptr[N] = E
}

__global__ __launch_bounds__(256) void scan3_kernel(const int* __restrict__ cnt,
                                                    const int* __restrict__ bsum,
                                                    int* __restrict__ rowptr,
                                                    int* __restrict__ cursor, int N)
{
    __shared__ int sthr[256];
    const int b = blockIdx.x, t = threadIdx.x;
    const int base = b * 1024 + t * 4;
    int loc[4]; int run = 0;
    #pragma unroll
    for (int j = 0; j < 4; ++j) {
        int g = base + j;
        int c = (g < N) ? cnt[g] : 0;
        loc[j] = run; run += c;
    }
    sthr[t] = run; __syncthreads();
    int own = run;
    for (int o = 1; o < 256; o <<= 1) {
        int x = (t >= o) ? sthr[t - o] : 0;
        __syncthreads();
        sthr[t] += x;
        __syncthreads();
    }
    int ex = sthr[t] - own + bsum[b];
    #pragma unroll
    for (int j = 0; j < 4; ++j) {
        int g = base + j;
        if (g < N) { rowptr[g] = ex + loc[j]; cursor[g] = ex + loc[j]; }
    }
}

__global__ void scatter_kernel(const float* __restrict__ ef, const int* __restrict__ ei,
                               int* __restrict__ cursor, float* __restrict__ efp,
                               int* __restrict__ srcp, int E)
{
    int e = blockIdx.x * blockDim.x + threadIdx.x;
    if (e < E) {
        int tg = ei[E + e];
        int pos = atomicAdd(&cursor[tg], 1);
        efp[pos] = ef[e];
        srcp[pos] = ei[e];
    }
}

// ---------------------------------------------------------------------------
// Fused bipartite layer, v2 (low-LDS, chunked gathers).
// Block owns 64 consecutive TARGET nodes = contiguous CSR edge range.
// Phase A: msg = relu(src + bn(h(ef))), mean-aggregated into LDS; PQ read
//   from global (L1/L2-hot); 16-deep branch-free gather batches.
// Phase B: o = M@lW, then (sU<-rW, sAgg<-tgt) o += T@rW, L2-normalize, relu.
// Phase C (FUSE_ACC): acc += newTgt @ accW.   Requires N < 2^18.
// LDS ~34.8 KB -> 4 blocks/CU.
// ---------------------------------------------------------------------------
template <bool FUSE_ACC>
__global__ __launch_bounds__(256) void layer_kernel(
    const float* __restrict__ efp, const int* __restrict__ srcp,
    const int* __restrict__ rowptr, const float* __restrict__ src,
    float* __restrict__ tgt,
    const float* __restrict__ PQ, const float* __restrict__ sortedT,
    const float* __restrict__ st,
    const float* __restrict__ lW, const float* __restrict__ lb,
    const float* __restrict__ rW,
    const float* __restrict__ accW, float* __restrict__ acc, int N)
{
    __shared__ float sU[4096];          // staged weights: lW -> rW -> accW
    __shared__ float sAgg[64][65];      // M -> old tgt -> staged out -> new tgt
    __shared__ float sT[64];
    __shared__ int   sRp[65];
    __shared__ float part[4][64];
    __shared__ float srn[64];

    const int t = threadIdx.x, lane = t & 63, wave = t >> 6;
    const int n0 = blockIdx.x * 64;
    const float2* __restrict__ PQg = (const float2*)PQ;

    for (int i = t; i < 64 * 65; i += 256) (&sAgg[0][0])[i] = 0.f;
    if (t < 64) sT[t] = sortedT[t];
    if (t < 65) sRp[t] = rowptr[min(n0 + t, N)];
    __syncthreads();

    const float ssv = st[lane], ttv = st[64 + lane];
    const int e0 = sRp[0], e1 = sRp[64];
    float racc = 0.f;
    for (int tb = e0 + wave * 64; tb < e1; tb += 256) {
        const int m = min(64, e1 - tb);
        float ev = 0.f; unsigned pk = 0; bool bndb = false;
        if (lane < m) {
            int g = tb + lane;
            ev = efp[g];
            unsigned is = (unsigned)srcp[g];
            int lo = 0;                         // binary ascent: sRp[lo] <= g < sRp[lo+1]
            #pragma unroll
            for (int s = 32; s >= 1; s >>= 1) {
                int c = lo + s;
                if (c <= 63 && sRp[c] <= g) lo = c;
            }
            bndb = (g + 1 == sRp[lo + 1]);
            unsigned iv = (unsigned)interval_of(sT, ev);
            pk = is | (iv << 18) | ((unsigned)lo << 25) | (bndb ? (1u << 31) : 0u);
        }
        const unsigned long long bm = __ballot(bndb);
        for (int c = 0; c < m; c += 16) {
            if (c + 16 <= m) {
                float msg[16];
                #pragma unroll
                for (int k = 0; k < 16; ++k) {   // branch-free: 16 gathers in flight
                    float sev = readlane_f(ev, c + k);
                    unsigned spk = readlane_u(pk, c + k);
                    float2 pq = PQg[((spk >> 18) & 0x7Fu) * 64 + lane];
                    float h = fmaxf(fmaf(sev, pq.x, pq.y), 0.f);
                    msg[k] = fmaxf(src[(size_t)(spk & 0x3FFFFu) * 64 + lane]
                                   + fmaf(h, ssv, ttv), 0.f);
                }
                #pragma unroll
                for (int k = 0; k < 16; ++k) {   // scan + row-end flush
                    racc += msg[k];
                    if ((bm >> (c + k)) & 1ull) {
                        unsigned spk = readlane_u(pk, c + k);
                        int l = (int)((spk >> 25) & 63u);
                        float inv = 1.f / (float)(sRp[l + 1] - sRp[l]);
                        atomicAdd(&sAgg[l][lane], racc * inv);
                        racc = 0.f;
                    }
                }
            } else {
                for (int k = c; k < m; ++k) {
                    float sev = readlane_f(ev, k);
                    unsigned spk = readlane_u(pk, k);
                    float2 pq = PQg[((spk >> 18) & 0x7Fu) * 64 + lane];
                    float h = fmaxf(fmaf(sev, pq.x, pq.y), 0.f);
                    float msg = fmaxf(src[(size_t)(spk & 0x3FFFFu) * 64 + lane]
                                      + fmaf(h, ssv, ttv), 0.f);
                    racc += msg;
                    if ((bm >> k) & 1ull) {
                        int l = (int)((spk >> 25) & 63u);
                        float inv = 1.f / (float)(sRp[l + 1] - sRp[l]);
                        atomicAdd(&sAgg[l][lane], racc * inv);
                        racc = 0.f;
                    }
                }
            }
        }
        if (racc != 0.f) {                      // tile ended mid-row: flush partial
            unsigned spk = readlane_u(pk, m - 1);
            int l = (int)((spk >> 25) & 63u);
            float inv = 1.f / (float)(sRp[l + 1] - sRp[l]);
            atomicAdd(&sAgg[l][lane], racc * inv);
            racc = 0.f;
        }
    }
    __syncthreads();

    // ---- phase B1: o = M @ lW ----
    for (int idx = t; idx < 4096; idx += 256) sU[idx] = lW[idx];
    __syncthreads();
    const int n = lane;
    float o[16];
    {
        const float* mr = sAgg[n];
        for (int m4 = 0; m4 < 4; ++m4) {
            const int kb = (wave + m4 * 4) * 4;
            float o0 = 0, o1 = 0, o2 = 0, o3 = 0;
            #pragma unroll 8
            for (int j = 0; j < 64; ++j) {
                float mv = mr[j];
                float4 w4 = *reinterpret_cast<const float4*>(&sU[j * 64 + kb]);
                o0 = fmaf(mv, w4.x, o0); o1 = fmaf(mv, w4.y, o1);
                o2 = fmaf(mv, w4.z, o2); o3 = fmaf(mv, w4.w, o3);
            }
            o[m4 * 4 + 0] = o0; o[m4 * 4 + 1] = o1;
            o[m4 * 4 + 2] = o2; o[m4 * 4 + 3] = o3;
        }
    }
    __syncthreads();                    // M + lW reads complete
    // ---- phase B2: sU <- rW, sAgg <- old tgt; o += T @ rW ----
    for (int idx = t; idx < 4096; idx += 256) sU[idx] = rW[idx];
    for (int idx = t; idx < 4096; idx += 256) {
        int nn = idx >> 6, j = idx & 63;
        int gn = n0 + nn;
        sAgg[nn][j] = (gn < N) ? tgt[(size_t)gn * 64 + j] : 0.f;
    }
    __syncthreads();
    float ssq = 0.f;
    {
        const float* tr = sAgg[n];
        for (int m4 = 0; m4 < 4; ++m4) {
            const int kb = (wave + m4 * 4) * 4;
            float o0 = o[m4 * 4 + 0], o1 = o[m4 * 4 + 1];
            float o2 = o[m4 * 4 + 2], o3 = o[m4 * 4 + 3];
            #pragma unroll 8
            for (int j = 0; j < 64; ++j) {
                float tv = tr[j];
                float4 w4 = *reinterpret_cast<const float4*>(&sU[j * 64 + kb]);
                o0 = fmaf(tv, w4.x, o0); o1 = fmaf(tv, w4.y, o1);
                o2 = fmaf(tv, w4.z, o2); o3 = fmaf(tv, w4.w, o3);
            }
            o0 += lb[kb + 0]; o1 += lb[kb + 1]; o2 += lb[kb + 2]; o3 += lb[kb + 3];
            o[m4 * 4 + 0] = o0; o[m4 * 4 + 1] = o1;
            o[m4 * 4 + 2] = o2; o[m4 * 4 + 3] = o3;
            ssq = fmaf(o0, o0, fmaf(o1, o1, fmaf(o2, o2, fmaf(o3, o3, ssq))));
        }
    }
    part[wave][n] = ssq;
    __syncthreads();                    // T + rW reads complete
    if (t < 64) {
        float s = part[0][t] + part[1][t] + part[2][t] + part[3][t];
        srn[t] = 1.f / fmaxf(sqrtf(s), 1e-12f);
    }
    for (int m4 = 0; m4 < 4; ++m4) {    // stage raw o (overwrite tgt staging)
        const int kb = (wave + m4 * 4) * 4;
        sAgg[n][kb + 0] = o[m4 * 4 + 0];
        sAgg[n][kb + 1] = o[m4 * 4 + 1];
        sAgg[n][kb + 2] = o[m4 * 4 + 2];
        sAgg[n][kb + 3] = o[m4 * 4 + 3];
    }
    __syncthreads();
    for (int idx = t; idx < 4096; idx += 256) {   // coalesced normalize+store
        int nn = idx >> 6, k = idx & 63;
        int gn = n0 + nn;
        float v = fmaxf((&sAgg[0][0])[nn * 65 + k] * srn[nn], 0.f);
        if (gn < N) tgt[(size_t)gn * 64 + k] = v;
        if (FUSE_ACC) (&sAgg[0][0])[nn * 65 + k] = v;   // keep normalized for gemm
    }
    if (FUSE_ACC) {
        __syncthreads();
        for (int idx = t; idx < 4096; idx += 256) sU[idx] = accW[idx];
        __syncthreads();
        const float* xr = sAgg[n];
        const int gn = n0 + n;
        for (int m4 = 0; m4 < 4; ++m4) {
            const int kb = (wave + m4 * 4) * 4;
            float o0 = 0, o1 = 0, o2 = 0, o3 = 0;
            #pragma unroll 8
            for (int j = 0; j < 64; ++j) {
                float xv = xr[j];
                float4 w4 = *reinterpret_cast<const float4*>(&sU[j * 64 + kb]);
                o0 = fmaf(xv, w4.x, o0); o1 = fmaf(xv, w4.y, o1);
                o2 = fmaf(xv, w4.z, o2); o3 = fmaf(xv, w4.w, o3);
            }
            if (gn < N) {
                float4* ap = reinterpret_cast<float4*>(&acc[(size_t)gn * 64 + kb]);
                float4 old = *ap;
                *ap = make_float4(old.x + o0, old.y + o1, old.z + o2, old.w + o3);
            }
        }
    }
}

// ---------------------------------------------------------------------------
// acc = X @ W   (initial lin1 block, x_var[0])
// ---------------------------------------------------------------------------
__global__ __launch_bounds__(256) void acc_gemm_init_kernel(
    const float* __restrict__ X, const float* __restrict__ W,
    float* __restrict__ acc, int N)
{
    __shared__ float sW[64 * 64];
    __shared__ float sX[64][65];
    const int n0 = blockIdx.x * 64;
    const int t = threadIdx.x;
    for (int idx = t; idx < 4096; idx += 256) sW[idx] = W[idx];
    for (int idx = t; idx < 4096; idx += 256) {
        int n = idx >> 6, j = idx & 63;
        int gn = n0 + n;
        sX[n][j] = (gn < N) ? X[gn * 64 + j] : 0.f;
    }
    __syncthreads();
    const int n = t & 63;
    const int gn = n0 + n;
    for (int m4 = 0; m4 < 4; ++m4) {
        int kb = ((t >> 6) + m4 * 4) * 4;
        float o0 = 0, o1 = 0, o2 = 0, o3 = 0;
        const float* xr = sX[n];
        #pragma unroll 8
        for (int j = 0; j < 64; ++j) {
            float xv = xr[j];
            float4 w4 = *reinterpret_cast<const float4*>(&sW[j * 64 + kb]);
            o0 = fmaf(xv, w4.x, o0); o1 = fmaf(xv, w4.y, o1);
            o2 = fmaf(xv, w4.z, o2); o3 = fmaf(xv, w4.w, o3);
        }
        if (gn < N)
            *reinterpret_cast<float4*>(&acc[(size_t)gn * 64 + kb]) =
                make_float4(o0, o1, o2, o3);
    }
}

// ---------------------------------------------------------------------------
// final head: relu(acc+b1) -> relu(@W2+b2) -> relu(@W3+b3) -> @W4+b4 -> logsoftmax
// ---------------------------------------------------------------------------
__global__ __launch_bounds__(256) void final_kernel(
    const float* __restrict__ acc, const float* __restrict__ b1,
    const float* __restrict__ W2, const float* __restrict__ b2,
    const float* __restrict__ W3, const float* __restrict__ b3,
    const float* __restrict__ W4, const float* __restrict__ b4,
    float* __restrict__ out, int N)
{
    __shared__ float sW[64 * 64];
    __shared__ float sA[64][65], sB[64][65];
    __shared__ float sy[64][2];
    const int n0 = blockIdx.x * 64;
    const int t = threadIdx.x;
    for (int idx = t; idx < 4096; idx += 256) sW[idx] = W2[idx];
    for (int idx = t; idx < 4096; idx += 256) {
        int n = idx >> 6, j = idx & 63;
        int gn = n0 + n;
        sA[n][j] = (gn < N) ? fmaxf(acc[gn * 64 + j] + b1[j], 0.f) : 0.f;
    }
    __syncthreads();
    const int n = t & 63;
    for (int m4 = 0; m4 < 4; ++m4) {
        int kb = ((t >> 6) + m4 * 4) * 4;
        float o0 = 0, o1 = 0, o2 = 0, o3 = 0;
        const float* xr = sA[n];
        #pragma unroll 8
        for (int j = 0; j < 64; ++j) {
            float xv = xr[j];
            float4 w4 = *reinterpret_cast<const float4*>(&sW[j * 64 + kb]);
            o0 = fmaf(xv, w4.x, o0); o1 = fmaf(xv, w4.y, o1);
            o2 = fmaf(xv, w4.z, o2); o3 = fmaf(xv, w4.w, o3);
        }
        sB[n][kb + 0] = fmaxf(o0 + b2[kb + 0], 0.f);
        sB[n][kb + 1] = fmaxf(o1 + b2[kb + 1], 0.f);
        sB[n][kb + 2] = fmaxf(o2 + b2[kb + 2], 0.f);
        sB[n][kb + 3] = fmaxf(o3 + b2[kb + 3], 0.f);
    }
    __syncthreads();
    for (int idx = t; idx < 4096; idx += 256) sW[idx] = W3[idx];
    __syncthreads();
    for (int m4 = 0; m4 < 4; ++m4) {
        int kb = ((t >> 6) + m4 * 4) * 4;
        float o0 = 0, o1 = 0, o2 = 0, o3 = 0;
        const float* xr = sB[n];
        #pragma unroll 8
        for (int j = 0; j < 64; ++j) {
            float xv = xr[j];
            float4 w4 = *reinterpret_cast<const float4*>(&sW[j * 64 + kb]);
            o0 = fmaf(xv, w4.x, o0); o1 = fmaf(xv, w4.y, o1);
            o2 = fmaf(xv, w4.z, o2); o3 = fmaf(xv, w4.w, o3);
        }
        sA[n][kb + 0] = fmaxf(o0 + b3[kb + 0], 0.f);
        sA[n][kb + 1] = fmaxf(o1 + b3[kb + 1], 0.f);
        sA[n][kb + 2] = fmaxf(o2 + b3[kb + 2], 0.f);
        sA[n][kb + 3] = fmaxf(o3 + b3[kb + 3], 0.f);
    }
    __syncthreads();
    if (t < 128) {
        int nn = t >> 1, c = t & 1;
        float a = b4[c];
        for (int j = 0; j < 64; ++j) a = fmaf(sA[nn][j], W4[j * 2 + c], a);
        sy[nn][c] = a;
    }
    __syncthreads();
    if (t < 64) {
        int gn = n0 + t;
        if (gn < N) {
            float y0 = sy[t][0], y1 = sy[t][1];
            float m = fmaxf(y0, y1);
            float lse = m + logf(expf(y0 - m) + expf(y1 - m));
            out[gn * 2 + 0] = y0 - lse;
            out[gn * 2 + 1] = y1 - lse;
        }
    }
}

// ---------------------------------------------------------------------------
extern "C" void kernel_launch(void* const* d_in, const int* in_sizes, int n_in,
                              void* d_out, int out_size, void* d_ws, size_t ws_size,
                              hipStream_t stream)
{
    const float* varf    = (const float*)d_in[0];
    const float* conf    = (const float*)d_in[1];
    const float* ev_feat = (const float*)d_in[2];
    const float* ec_feat = (const float*)d_in[3];
    const int*   ei_var  = (const int*)d_in[4];
    const int*   ei_con  = (const int*)d_in[5];
    const float* enc_v_W1 = (const float*)d_in[6];
    const float* enc_v_b1 = (const float*)d_in[7];
    const float* enc_v_W2 = (const float*)d_in[8];
    const float* enc_v_b2 = (const float*)d_in[9];
    const float* enc_c_W1 = (const float*)d_in[10];
    const float* enc_c_b1 = (const float*)d_in[11];
    const float* enc_c_W2 = (const float*)d_in[12];
    const float* enc_c_b2 = (const float*)d_in[13];
    const float* lv_eW1 = (const float*)d_in[14];
    const float* lv_eb1 = (const float*)d_in[15];
    const float* lv_eW2 = (const float*)d_in[16];
    const float* lv_eb2 = (const float*)d_in[17];
    const float* lv_g   = (const float*)d_in[18];
    const float* lv_bt  = (const float*)d_in[19];
    const float* lv_lW  = (const float*)d_in[20];
    const float* lv_lb  = (const float*)d_in[21];
    const float* lv_rW  = (const float*)d_in[22];
    const float* lc_eW1 = (const float*)d_in[23];
    const float* lc_eb1 = (const float*)d_in[24];
    const float* lc_eW2 = (const float*)d_in[25];
    const float* lc_eb2 = (const float*)d_in[26];
    const float* lc_g   = (const float*)d_in[27];
    const float* lc_bt  = (const float*)d_in[28];
    const float* lc_lW  = (const float*)d_in[29];
    const float* lc_lb  = (const float*)d_in[30];
    const float* lc_rW  = (const float*)d_in[31];
    const float* lin1_W = (const float*)d_in[32];
    const float* lin1_b = (const float*)d_in[33];
    const float* lin2_W = (const float*)d_in[34];
    const float* lin2_b = (const float*)d_in[35];
    const float* lin3_W = (const float*)d_in[36];
    const float* lin3_b = (const float*)d_in[37];
    const float* lin4_W = (const float*)d_in[38];
    const float* lin4_b = (const float*)d_in[39];

    const int Nv = in_sizes[0] / 2, Nc = in_sizes[1] / 2;
    const int Ev = in_sizes[2], Ec = in_sizes[3];
    const int maxN = (Nv > Nc) ? Nv : Nc;
    const int NSB = 128;   // stats blocks per config

    // ---- workspace budget check (total ~99.7 MB at nominal sizes) ----
    size_t need = (size_t)(8 * NSB * 2 * 64) * 8;                      // stage (doubles)
    need += ((size_t)Nv * 64 * 2 + (size_t)Nc * 64) * 4;               // xv, acc, xc
    need += (size_t)(8 * 65 * 128 + 8 * 64 + 8 * 128) * 4;             // PQ8, sortedT8, stv
    need += ((size_t)Ev * 2 + (size_t)Ec * 2) * 4;                     // efp+srcp, both graphs
    need += ((size_t)Nc + 1 + (size_t)Nv + 1) * 4;                     // rowptrs
    need += ((size_t)maxN * 2 + 1024) * 4;                             // cnt, cursor, bsum
    if (ws_size < need) {   // clean visible failure instead of container-killing OOB
        hipMemsetAsync(d_out, 0, (size_t)out_size * sizeof(float), stream);
        return;
    }

    double* stage = (double*)d_ws;
    float* ws = (float*)(stage + (size_t)8 * NSB * 2 * 64);
    float* xv  = ws;  ws += (size_t)Nv * 64;
    float* xc  = ws;  ws += (size_t)Nc * 64;
    float* acc = ws;  ws += (size_t)Nv * 64;
    float* PQ8 = ws;      ws += 8 * 65 * 128;
    float* sortedT8 = ws; ws += 8 * 64;
    float* stv = ws;      ws += 8 * 128;
    float* efp_v = ws;            ws += Ev;
    int*   srcp_v = (int*)ws;     ws += Ev;
    float* efp_c = ws;            ws += Ec;
    int*   srcp_c = (int*)ws;     ws += Ec;
    int*   rowptr_v = (int*)ws;   ws += Nc + 1;
    int*   rowptr_c = (int*)ws;   ws += Nv + 1;
    int*   cnt    = (int*)ws;     ws += maxN;
    int*   cursor = (int*)ws;     ws += maxN;
    int*   bsum   = (int*)ws;     ws += 1024;

    const dim3 blk(256);
    const int gbV = (Nv + 63) / 64, gbC = (Nc + 63) / 64;

    enc_kernel<<<gbV, blk, 0, stream>>>(varf, enc_v_W1, enc_v_b1, enc_v_W2, enc_v_b2, xv, Nv);
    enc_kernel<<<gbC, blk, 0, stream>>>(conf, enc_c_W1, enc_c_b1, enc_c_W2, enc_c_b2, xc, Nc);

    // ---- CSR build: var-graph (targets = con), con-graph (targets = var) ----
    {
        hipMemsetAsync(cnt, 0, (size_t)Nc * sizeof(int), stream);
        count_kernel<<<(Ev + 255) / 256, blk, 0, stream>>>(ei_var + Ev, cnt, Ev);
        int G = (Nc + 1023) / 1024;
        scan1_kernel<<<G, blk, 0, stream>>>(cnt, bsum, Nc);
        scan2_kernel<<<1, 1024, 0, stream>>>(bsum, G, rowptr_v + Nc, Ev);
        scan3_kernel<<<G, blk, 0, stream>>>(cnt, bsum, rowptr_v, cursor, Nc);
        scatter_kernel<<<(Ev + 255) / 256, blk, 0, stream>>>(ev_feat, ei_var, cursor,
                                                             efp_v, srcp_v, Ev);
        hipMemsetAsync(cnt, 0, (size_t)Nv * sizeof(int), stream);
        count_kernel<<<(Ec + 255) / 256, blk, 0, stream>>>(ei_con + Ec, cnt, Ec);
        G = (Nv + 1023) / 1024;
        scan1_kernel<<<G, blk, 0, stream>>>(cnt, bsum, Nv);
        scan2_kernel<<<1, 1024, 0, stream>>>(bsum, G, rowptr_c + Nv, Ec);
        scan3_kernel<<<G, blk, 0, stream>>>(cnt, bsum, rowptr_c, cursor, Nv);
        scatter_kernel<<<(Ec + 255) / 256, blk, 0, stream>>>(ec_feat, ei_con, cursor,
                                                             efp_c, srcp_c, Ec);
    }

    // ---- all 8 configs' edge-MLP tables + BN stats, batched upfront ----
    build_tables_all_kernel<<<8, blk, 0, stream>>>(
        lv_eW1, lv_eb1, lv_eW2, lv_eb2, lc_eW1, lc_eb1, lc_eW2, lc_eb2, PQ8, sortedT8);
    edge_stats_all_kernel<<<dim3(NSB, 8), blk, 0, stream>>>(
        ev_feat, ec_feat, Ev, Ec, PQ8, sortedT8, stage, NSB);
    bn_finalize_all_kernel<<<8, 128, 0, stream>>>(
        stage, NSB, lv_g, lv_bt, lc_g, lc_bt, Ev, Ec, stv);

    acc_gemm_init_kernel<<<gbV, blk, 0, stream>>>(xv, lin1_W, acc, Nv);

    for (int i = 0; i < 4; ++i) {
        // var -> con  (cfg = i): update xc from xv
        layer_kernel<false><<<gbC, blk, 0, stream>>>(
            efp_v, srcp_v, rowptr_v, xv, xc,
            PQ8 + i * 65 * 128, sortedT8 + i * 64, stv + i * 128,
            lv_lW + i * 4096, lv_lb + i * 64, lv_rW + i * 4096,
            nullptr, nullptr, Nc);
        // con -> var  (cfg = 4+i): update xv from xc, fuse acc += xv_new @ lin1_blk
        layer_kernel<true><<<gbV, blk, 0, stream>>>(
            efp_c, srcp_c, rowptr_c, xc, xv,
            PQ8 + (4 + i) * 65 * 128, sortedT8 + (4 + i) * 64, stv + (4 + i) * 128,
            lc_lW + i * 4096, lc_lb + i * 64, lc_rW + i * 4096,
            lin1_W + (i + 1) * 4096, acc, Nv);
    }

    final_kernel<<<gbV, blk, 0, stream>>>(acc, lin1_b, lin2_W, lin2_b,
                                          lin3_W, lin3_b, lin4_W, lin4_b,
                                          (float*)d_out, Nv);
}